// Round 2
// baseline (676.242 us; speedup 1.0000x reference)
//
#include <hip/hip_runtime.h>
#include <cstddef>
#include <cstdint>

#define B_ 16
#define H_ 16
#define NQ 8
#define D_ 128
#define E_ 2048
#define F3 6144
#define KVP 4096
#define KVT 4104
#define SCALE 0.08838834764831843f
#define NCHUNK 8
#define CHUNK 512
#define SUBR 32
#define NSUB 16
#define PARTSZ 1040  // 8 m + 8 l + 8*128 acc

// ---------------- GEMM: C[M][F] += X[M][K] * W[F][K]^T (fp32, split-K) ----------------
template <int BM, int BN, int SPLITK>
__global__ __launch_bounds__(256) void gemm_xwt(const float* __restrict__ X,
                                                const float* __restrict__ W,
                                                float* __restrict__ C,
                                                int K, int Fdim) {
  constexpr int BK = 32;
  constexpr int RM = BM / 16;
  constexpr int RN = BN / 16;
  __shared__ float xs[BK][BM + 4];
  __shared__ float wss[BK][BN + 4];
  const int t = threadIdx.x;
  const int tm = t >> 4, tn = t & 15;
  const int m0 = blockIdx.y * BM, f0 = blockIdx.x * BN;
  const int kbeg = blockIdx.z * (K / SPLITK), kend = kbeg + K / SPLITK;
  float acc[RM][RN];
#pragma unroll
  for (int i = 0; i < RM; ++i)
#pragma unroll
    for (int j = 0; j < RN; ++j) acc[i][j] = 0.f;

  for (int kk = kbeg; kk < kend; kk += BK) {
#pragma unroll
    for (int i = 0; i < (BM * BK) / 1024; ++i) {
      int j = t + i * 256;
      int r = j >> 3;
      int c = (j & 7) << 2;
      float4 v = *reinterpret_cast<const float4*>(&X[(size_t)(m0 + r) * K + kk + c]);
      xs[c + 0][r] = v.x; xs[c + 1][r] = v.y; xs[c + 2][r] = v.z; xs[c + 3][r] = v.w;
    }
#pragma unroll
    for (int i = 0; i < (BN * BK) / 1024; ++i) {
      int j = t + i * 256;
      int r = j >> 3;
      int c = (j & 7) << 2;
      float4 v = *reinterpret_cast<const float4*>(&W[(size_t)(f0 + r) * K + kk + c]);
      wss[c + 0][r] = v.x; wss[c + 1][r] = v.y; wss[c + 2][r] = v.z; wss[c + 3][r] = v.w;
    }
    __syncthreads();
#pragma unroll
    for (int k = 0; k < BK; ++k) {
      float xv[RM], wv[RN];
      if constexpr (RM == 4) {
        *reinterpret_cast<float4*>(xv) = *reinterpret_cast<const float4*>(&xs[k][tm * 4]);
      } else {
        *reinterpret_cast<float2*>(xv) = *reinterpret_cast<const float2*>(&xs[k][tm * 2]);
      }
      if constexpr (RN == 4) {
        *reinterpret_cast<float4*>(wv) = *reinterpret_cast<const float4*>(&wss[k][tn * 4]);
      } else {
        *reinterpret_cast<float2*>(wv) = *reinterpret_cast<const float2*>(&wss[k][tn * 2]);
      }
#pragma unroll
      for (int i = 0; i < RM; ++i)
#pragma unroll
        for (int j = 0; j < RN; ++j) acc[i][j] += xv[i] * wv[j];
    }
    __syncthreads();
  }
#pragma unroll
  for (int i = 0; i < RM; ++i) {
    float* cp = &C[(size_t)(m0 + tm * RM + i) * Fdim + f0 + tn * RN];
    if constexpr (SPLITK == 1) {
      if constexpr (RN == 4) {
        *reinterpret_cast<float4*>(cp) = make_float4(acc[i][0], acc[i][1], acc[i][2], acc[i][3]);
      } else {
        *reinterpret_cast<float2*>(cp) = make_float2(acc[i][0], acc[i][1]);
      }
    } else {
#pragma unroll
      for (int j = 0; j < RN; ++j) atomicAdd(cp + j, acc[i][j]);
    }
  }
}

// ------- Fused KV-cache copy + flash-attention partials over past chunks -------
// grid: (NCHUNK, H, B), 256 threads. K never goes to LDS: scores are computed on
// the staged registers (column g = t&31 is fixed per thread) against Q held in VGPRs.
__global__ __launch_bounds__(256, 3) void attn_partial(
    const float* __restrict__ past_k, const float* __restrict__ past_v,
    const float* __restrict__ qkv, float* __restrict__ out_k,
    float* __restrict__ out_v, float* __restrict__ part) {
  const int t = threadIdx.x;
  const int c = blockIdx.x, h = blockIdx.y, b = blockIdx.z;
  const int bh = b * H_ + h;
  const int g = t & 31, rg = t >> 5;

  __shared__ float v_lds[SUBR * D_];   // 16KB linear [row][d]; reused for final reduce
  __shared__ float s_lds[SUBR * 9];    // raw scores, pad 9 (odd -> conflict-free strided read)
  __shared__ float p_lds[SUBR * 12];   // [row][qi] padded to 12 (16B-aligned f4 reads)
  __shared__ float cm_lds[NQ], cs_lds[NQ];
  __shared__ float m_lds[2][NQ], l_lds[2][NQ];

  // Q resident in registers: this thread's fixed f4-column for all 8 q-rows
  float4 qreg[NQ];
#pragma unroll
  for (int qi = 0; qi < NQ; ++qi)
    qreg[qi] = *reinterpret_cast<const float4*>(
        &qkv[(size_t)(b * NQ + qi) * F3 + h * D_ + g * 4]);

  if (t < NQ) { m_lds[0][t] = -1e30f; l_lds[0][t] = 0.f; }

  const float* gk = past_k + ((size_t)bh * KVP + (size_t)c * CHUNK) * D_;
  const float* gv = past_v + ((size_t)bh * KVP + (size_t)c * CHUNK) * D_;
  float* ok = out_k + ((size_t)bh * KVT + (size_t)c * CHUNK) * D_;
  float* ov = out_v + ((size_t)bh * KVT + (size_t)c * CHUNK) * D_;

  const int w = t >> 6;               // wave id: PV row-slice owner
  const int lqg = (t >> 5) & 1;       // PV: q-group within wave
  const int dq = t & 31;              // PV: f4 d-column
  float acc[4][4];
#pragma unroll
  for (int i = 0; i < 4; ++i)
#pragma unroll
    for (int j = 0; j < 4; ++j) acc[i][j] = 0.f;

  const int b0 = g & 1, b1 = (g >> 1) & 1, b2 = (g >> 2) & 1;
  const int qsel = 4 * b0 + 2 * b1 + b2;  // qi this lane's reduced value maps to

  __syncthreads();

  for (int sub = 0; sub < NSUB; ++sub) {
    const int cur = sub & 1, nxt = cur ^ 1;
    const size_t off = (size_t)sub * SUBR * D_;

    // ---- phase A: preload 4 K/V rows, copy-through to cache, V->LDS, reg-direct scores ----
    float4 kf[4], vf[4];
#pragma unroll
    for (int i = 0; i < 4; ++i) {
      const size_t ga = off + (size_t)(rg + 8 * i) * D_ + g * 4;
      kf[i] = *reinterpret_cast<const float4*>(&gk[ga]);
      vf[i] = *reinterpret_cast<const float4*>(&gv[ga]);
    }
#pragma unroll
    for (int i = 0; i < 4; ++i) {
      const int r = rg + 8 * i;
      const size_t ga = off + (size_t)r * D_ + g * 4;
      *reinterpret_cast<float4*>(&ok[ga]) = kf[i];
      *reinterpret_cast<float4*>(&ov[ga]) = vf[i];
      *reinterpret_cast<float4*>(&v_lds[r * D_ + g * 4]) = vf[i];
      float sp[NQ];
#pragma unroll
      for (int qi = 0; qi < NQ; ++qi)
        sp[qi] = kf[i].x * qreg[qi].x + kf[i].y * qreg[qi].y +
                 kf[i].z * qreg[qi].z + kf[i].w * qreg[qi].w;
      // butterfly 8 vals -> 1 per lane over 32 lanes (row-group)
      float v1[4];
#pragma unroll
      for (int j = 0; j < 4; ++j) {
        float x = b0 ? sp[j] : sp[j + 4];
        v1[j] = (b0 ? sp[j + 4] : sp[j]) + __shfl_xor(x, 1);
      }
      float v2[2];
#pragma unroll
      for (int j = 0; j < 2; ++j) {
        float x = b1 ? v1[j] : v1[j + 2];
        v2[j] = (b1 ? v1[j + 2] : v1[j]) + __shfl_xor(x, 2);
      }
      float v3;
      {
        float x = b2 ? v2[0] : v2[1];
        v3 = (b2 ? v2[1] : v2[0]) + __shfl_xor(x, 4);
      }
      v3 += __shfl_xor(v3, 8);
      v3 += __shfl_xor(v3, 16);
      if (g < 8) s_lds[r * 9 + qsel] = v3;
    }
    __syncthreads();  // B1: s_lds + v_lds ready

    // ---- phase B: softmax over this subtile ----
    {
      const int srow = t & 31, sqi = t >> 5;
      float s = s_lds[srow * 9 + sqi] * SCALE;
      float cmax = s;
#pragma unroll
      for (int o = 16; o > 0; o >>= 1) cmax = fmaxf(cmax, __shfl_xor(cmax, o));
      float mo = m_lds[cur][sqi];
      float mn = fmaxf(mo, cmax);
      float p = __expf(s - mn);
      float psum = p;
#pragma unroll
      for (int o = 16; o > 0; o >>= 1) psum += __shfl_xor(psum, o);
      p_lds[srow * 12 + sqi] = p;
      if (srow == 0) { cm_lds[sqi] = cmax; cs_lds[sqi] = psum; }
    }
    __syncthreads();  // B2: p/cm/cs ready

    // ---- phase C: PV accumulate; wave w owns rows [8w, 8w+8) ----
    {
#pragma unroll
      for (int jq = 0; jq < 4; ++jq) {
        const int qi = lqg * 4 + jq;
        float mo = m_lds[cur][qi];
        float f = __expf(mo - fmaxf(mo, cm_lds[qi]));
        acc[jq][0] *= f; acc[jq][1] *= f; acc[jq][2] *= f; acc[jq][3] *= f;
      }
#pragma unroll
      for (int r8 = 0; r8 < 8; ++r8) {
        const int r = w * 8 + r8;
        float4 p4 = *reinterpret_cast<const float4*>(&p_lds[r * 12 + lqg * 4]);
        float4 v4 = *reinterpret_cast<const float4*>(&v_lds[r * D_ + dq * 4]);
        acc[0][0] += p4.x * v4.x; acc[0][1] += p4.x * v4.y; acc[0][2] += p4.x * v4.z; acc[0][3] += p4.x * v4.w;
        acc[1][0] += p4.y * v4.x; acc[1][1] += p4.y * v4.y; acc[1][2] += p4.y * v4.z; acc[1][3] += p4.y * v4.w;
        acc[2][0] += p4.z * v4.x; acc[2][1] += p4.z * v4.y; acc[2][2] += p4.z * v4.z; acc[2][3] += p4.z * v4.w;
        acc[3][0] += p4.w * v4.x; acc[3][1] += p4.w * v4.y; acc[3][2] += p4.w * v4.z; acc[3][3] += p4.w * v4.w;
      }
      if (t < NQ) {
        float mo = m_lds[cur][t];
        float mn = fmaxf(mo, cm_lds[t]);
        l_lds[nxt][t] = l_lds[cur][t] * __expf(mo - mn) + cs_lds[t];
        m_lds[nxt][t] = mn;
      }
    }
    __syncthreads();  // B3: PV done before LDS overwrite
  }

  // ---- cross-wave partial-sum reduce through v_lds (exactly 4x1024 floats) ----
#pragma unroll
  for (int jq = 0; jq < 4; ++jq)
    *reinterpret_cast<float4*>(&v_lds[w * 1024 + (lqg * 4 + jq) * D_ + dq * 4]) =
        make_float4(acc[jq][0], acc[jq][1], acc[jq][2], acc[jq][3]);
  __syncthreads();

  float* pb = part + ((size_t)bh * NCHUNK + c) * PARTSZ;
  if (t < NQ) { pb[t] = m_lds[0][t]; pb[8 + t] = l_lds[0][t]; }  // NSUB even -> slot 0
  {
    float4 s0 = *reinterpret_cast<const float4*>(&v_lds[t * 4]);
    float4 s1 = *reinterpret_cast<const float4*>(&v_lds[1024 + t * 4]);
    float4 s2 = *reinterpret_cast<const float4*>(&v_lds[2048 + t * 4]);
    float4 s3 = *reinterpret_cast<const float4*>(&v_lds[3072 + t * 4]);
    float4 r4 = make_float4(s0.x + s1.x + s2.x + s3.x, s0.y + s1.y + s2.y + s3.y,
                            s0.z + s1.z + s2.z + s3.z, s0.w + s1.w + s2.w + s3.w);
    *reinterpret_cast<float4*>(&pb[16 + t * 4]) = r4;
  }
}

// ------- new-token chunk + combine partials -> attention output (pre-proj) -------
// grid: (H, B), 256 threads.
__global__ __launch_bounds__(256) void attn_combine(
    const float* __restrict__ qkv, const float* __restrict__ part,
    float* __restrict__ out_k, float* __restrict__ out_v,
    float* __restrict__ attn) {
  const int t = threadIdx.x;
  const int h = blockIdx.x, b = blockIdx.y;
  const int bh = b * H_ + h;
  __shared__ float q_lds[NQ * 132];
  __shared__ float kn_lds[NQ * 132];
  __shared__ float vn_lds[NQ * 132];
  __shared__ float p9[NQ * 12];
  __shared__ float m9_lds[NQ], s9_lds[NQ];
  {
    int n = t >> 5, g = t & 31;
    const float* src = &qkv[(size_t)(b * NQ + n) * F3 + h * D_ + g * 4];
    float4 qv = *reinterpret_cast<const float4*>(src);
    float4 kv = *reinterpret_cast<const float4*>(src + E_);
    float4 vv = *reinterpret_cast<const float4*>(src + 2 * E_);
    *reinterpret_cast<float4*>(&q_lds[n * 132 + g * 4]) = qv;
    *reinterpret_cast<float4*>(&kn_lds[n * 132 + g * 4]) = kv;
    *reinterpret_cast<float4*>(&vn_lds[n * 132 + g * 4]) = vv;
    *reinterpret_cast<float4*>(&out_k[((size_t)bh * KVT + KVP + n) * D_ + g * 4]) = kv;
    *reinterpret_cast<float4*>(&out_v[((size_t)bh * KVT + KVP + n) * D_ + g * 4]) = vv;
  }
  __syncthreads();
  if (t < 64) {
    int nq = t >> 3, nk = t & 7;
    float s = 0.f;
#pragma unroll
    for (int g = 0; g < 32; ++g) {
      float4 qv = *reinterpret_cast<const float4*>(&q_lds[nq * 132 + g * 4]);
      float4 kv = *reinterpret_cast<const float4*>(&kn_lds[nk * 132 + g * 4]);
      s += qv.x * kv.x + qv.y * kv.y + qv.z * kv.z + qv.w * kv.w;
    }
    s *= SCALE;
    float mx = s;
#pragma unroll
    for (int o = 4; o > 0; o >>= 1) mx = fmaxf(mx, __shfl_xor(mx, o));
    float p = __expf(s - mx);
    float sm = p;
#pragma unroll
    for (int o = 4; o > 0; o >>= 1) sm += __shfl_xor(sm, o);
    p9[nk * 12 + nq] = p;
    if (nk == 0) { m9_lds[nq] = mx; s9_lds[nq] = sm; }
  }
  __syncthreads();
  const int qg = t >> 7, dcol = t & 127;
  const float* pb = part + (size_t)bh * NCHUNK * PARTSZ;
#pragma unroll
  for (int jq = 0; jq < 4; ++jq) {
    int qi = qg * 4 + jq;
    float M = m9_lds[qi];
#pragma unroll
    for (int c = 0; c < NCHUNK; ++c) M = fmaxf(M, pb[(size_t)c * PARTSZ + qi]);
    float num = 0.f, den = 0.f;
#pragma unroll
    for (int c = 0; c < NCHUNK; ++c) {
      const float* pc = pb + (size_t)c * PARTSZ;
      float wgt = __expf(pc[qi] - M);
      den += wgt * pc[8 + qi];
      num += wgt * pc[16 + (size_t)qi * D_ + dcol];
    }
    float acc9 = 0.f;
#pragma unroll
    for (int r = 0; r < NQ; ++r) acc9 += p9[r * 12 + qi] * vn_lds[r * 132 + dcol];
    float w9 = __expf(m9_lds[qi] - M);
    num += w9 * acc9;
    den += w9 * s9_lds[qi];
    attn[((size_t)(b * NQ + qi)) * E_ + h * D_ + dcol] = num / den;
  }
}

extern "C" void kernel_launch(void* const* d_in, const int* in_sizes, int n_in,
                              void* d_out, int out_size, void* d_ws, size_t ws_size,
                              hipStream_t stream) {
  const float* x      = (const float*)d_in[0];
  const float* past_k = (const float*)d_in[1];
  const float* past_v = (const float*)d_in[2];
  const float* W_qkv  = (const float*)d_in[3];
  const float* W_out  = (const float*)d_in[4];

  float* out   = (float*)d_out;
  float* out_k = out + (size_t)B_ * NQ * E_;
  float* out_v = out_k + (size_t)B_ * H_ * KVT * D_;

  float* ws   = (float*)d_ws;
  float* qkv  = ws;                                       // 786432 floats
  float* part = qkv + (size_t)B_ * NQ * F3;               // 2129920 floats
  float* attn = part + (size_t)B_ * H_ * NCHUNK * PARTSZ; // 262144 floats

  // zero split-K accumulation targets
  hipMemsetAsync(qkv, 0, (size_t)B_ * NQ * F3 * sizeof(float), stream);
  hipMemsetAsync(out, 0, (size_t)B_ * NQ * E_ * sizeof(float), stream);

  // 1) fused QKV projection (split-K=4, atomic accumulate)
  gemm_xwt<64, 64, 4><<<dim3(F3 / 64, 128 / 64, 4), 256, 0, stream>>>(x, W_qkv, qkv, E_, F3);
  // 2) fused KV-cache copy + flash partials over past chunks
  attn_partial<<<dim3(NCHUNK, H_, B_), 256, 0, stream>>>(past_k, past_v, qkv, out_k, out_v, part);
  // 3) new-token chunk + combine -> attention output (pre out-proj)
  attn_combine<<<dim3(H_, B_), 256, 0, stream>>>(qkv, part, out_k, out_v, attn);
  // 4) output projection (split-K=4, atomic accumulate)
  gemm_xwt<32, 32, 4><<<dim3(E_ / 32, 128 / 32, 4), 256, 0, stream>>>(attn, W_out, out, E_, E_);
}